// Round 1
// baseline (5003.317 us; speedup 1.0000x reference)
//
#include <hip/hip_runtime.h>
#include <math.h>

#define FEAT 64
#define CHEB_M 30
#define T_SCALE_D 5.0

// ---------------- CSR build ----------------

__global__ void hist_kernel(const int* __restrict__ rows, int* __restrict__ counts, int nnz) {
    int i = blockIdx.x * blockDim.x + threadIdx.x;
    int stride = gridDim.x * blockDim.x;
    for (; i < nnz; i += stride) atomicAdd(&counts[rows[i]], 1);
}

// Single-block 3-phase exclusive scan over N counts -> row_ptr[N+1], plus a
// cursor copy for the scatter pass. N ~ 100k, 1024 threads, ~98 elems/thread.
__global__ __launch_bounds__(1024) void scan_kernel(const int* __restrict__ counts,
                                                    int* __restrict__ row_ptr,
                                                    int* __restrict__ cursor, int N) {
    __shared__ int sums[1024];
    int t = threadIdx.x;
    int chunk = (N + 1023) >> 10;
    int begin = t * chunk;
    int end = begin + chunk;
    if (begin > N) begin = N;
    if (end > N) end = N;
    int local = 0;
    for (int i = begin; i < end; ++i) local += counts[i];
    sums[t] = local;
    __syncthreads();
    // Hillis-Steele inclusive scan over the 1024 thread sums
    for (int off = 1; off < 1024; off <<= 1) {
        int add = (t >= off) ? sums[t - off] : 0;
        __syncthreads();
        sums[t] += add;
        __syncthreads();
    }
    int prefix = (t == 0) ? 0 : sums[t - 1];
    for (int i = begin; i < end; ++i) {
        row_ptr[i] = prefix;
        cursor[i] = prefix;
        prefix += counts[i];
    }
    if (t == 0) row_ptr[N] = sums[1023];
}

__global__ void scatter_kernel(const int* __restrict__ rows, const int* __restrict__ cols,
                               const float* __restrict__ vals, int* __restrict__ cursor,
                               int* __restrict__ csr_col, float* __restrict__ csr_val, int nnz) {
    int i = blockIdx.x * blockDim.x + threadIdx.x;
    int stride = gridDim.x * blockDim.x;
    for (; i < nnz; i += stride) {
        int r = rows[i];
        int p = atomicAdd(&cursor[r], 1);
        csr_col[p] = cols[i];
        csr_val[p] = vals[i];
    }
}

// ---------------- Chebyshev steps ----------------
// One row per 64-lane group (4 rows per 256-thread block). Lane j owns
// feature j; every edge gather is one coalesced 256B read of t1[col][0:64].

// First step: T1 = spmm(X) - X; acc = c0*X + c1*T1  (acc fully overwritten)
__global__ void cheb_first(const float* __restrict__ X, float* __restrict__ t1buf,
                           float* __restrict__ acc, const int* __restrict__ row_ptr,
                           const int* __restrict__ csr_col, const float* __restrict__ csr_val,
                           float c0, float c1, int N) {
    int r = (blockIdx.x << 2) + (threadIdx.x >> 6);
    if (r >= N) return;
    int j = threadIdx.x & 63;
    int e0 = row_ptr[r], e1 = row_ptr[r + 1];
    float s = 0.f;
    for (int e = e0; e < e1; ++e)
        s += csr_val[e] * X[csr_col[e] * FEAT + j];
    int idx = r * FEAT + j;
    float xr = X[idx];
    float t1 = s - xr;
    t1buf[idx] = t1;
    acc[idx] = c0 * xr + c1 * t1;
}

// Generic step: tk = 2*spmm(t1) - 2*t1 - t0; acc += ck*tk; tnew = tk.
// NOTE: tnew may alias t0 (in-place ping-pong) -> t0/tnew NOT restrict.
// Each t0 element is read only by the exact thread that writes tnew there.
__global__ void cheb_step(const float* t0, const float* __restrict__ t1,
                          float* tnew, float* __restrict__ acc,
                          const int* __restrict__ row_ptr, const int* __restrict__ csr_col,
                          const float* __restrict__ csr_val, float ck, int N) {
    int r = (blockIdx.x << 2) + (threadIdx.x >> 6);
    if (r >= N) return;
    int j = threadIdx.x & 63;
    int e0 = row_ptr[r], e1 = row_ptr[r + 1];
    float s = 0.f;
    for (int e = e0; e < e1; ++e)
        s += csr_val[e] * t1[csr_col[e] * FEAT + j];
    int idx = r * FEAT + j;
    float t1r = t1[idx];
    float t0r = t0[idx];
    float tk = 2.f * s - 2.f * t1r - t0r;
    tnew[idx] = tk;
    acc[idx] += ck * tk;
}

extern "C" void kernel_launch(void* const* d_in, const int* in_sizes, int n_in,
                              void* d_out, int out_size, void* d_ws, size_t ws_size,
                              hipStream_t stream) {
    const int* rows = (const int*)d_in[0];
    const int* cols = (const int*)d_in[1];
    const float* vals = (const float*)d_in[2];
    const float* X = (const float*)d_in[3];
    int nnz = in_sizes[0];
    int Nd = in_sizes[3];
    int N = Nd / FEAT;
    float* acc = (float*)d_out;

    char* ws = (char*)d_ws;
    float* B0 = (float*)ws;
    float* B1 = (float*)(ws + (size_t)Nd * 4);
    int* row_ptr = (int*)(ws + (size_t)Nd * 8);
    int* cursor = row_ptr + (N + 1);
    int* counts = cursor + N;
    int* csr_col = counts + N;
    float* csr_val = (float*)(csr_col + nnz);

    // Static Chebyshev coefficients for exp(-t_scale * lambda), lambda_max=2.
    // T_k(x_j) = cos(k * pi * (j+0.5) / M) exactly at Chebyshev nodes.
    double c[CHEB_M];
    for (int k = 0; k < CHEB_M; ++k) {
        double sum = 0.0;
        for (int jj = 0; jj < CHEB_M; ++jj) {
            double theta = M_PI * (jj + 0.5) / CHEB_M;
            double lam = cos(theta) + 1.0;  // lambda_max/2 * (x+1)
            sum += exp(-T_SCALE_D * lam) * cos(k * theta);
        }
        c[k] = 2.0 / CHEB_M * sum;
    }
    c[0] *= 0.5;

    // CSR build (every launch; ~14MB traffic, cheap)
    hipMemsetAsync(counts, 0, (size_t)N * sizeof(int), stream);
    hist_kernel<<<2048, 256, 0, stream>>>(rows, counts, nnz);
    scan_kernel<<<1, 1024, 0, stream>>>(counts, row_ptr, cursor, N);
    scatter_kernel<<<2048, 256, 0, stream>>>(rows, cols, vals, cursor, csr_col, csr_val, nnz);

    int nblk = (N + 3) >> 2;
    // k = 0,1 fused
    cheb_first<<<nblk, 256, 0, stream>>>(X, B0, acc, row_ptr, csr_col, csr_val,
                                         (float)c[0], (float)c[1], N);
    // k = 2: t0 = X (read-only input), t1 = B0, write B1
    cheb_step<<<nblk, 256, 0, stream>>>(X, B0, B1, acc, row_ptr, csr_col, csr_val,
                                        (float)c[2], N);
    // k >= 3: tk overwrites the t0 buffer in place, then swap roles
    const float* t0p = B0;
    const float* t1p = B1;
    for (int k = 3; k < CHEB_M; ++k) {
        cheb_step<<<nblk, 256, 0, stream>>>(t0p, t1p, (float*)t0p, acc, row_ptr,
                                            csr_col, csr_val, (float)c[k], N);
        const float* tmp = t0p; t0p = t1p; t1p = tmp;
    }
}

// Round 2
// 2547.989 us; speedup vs baseline: 1.9636x; 1.9636x over previous
//
#include <hip/hip_runtime.h>
#include <math.h>

#define FEAT 64
#define CHEB_M 30
#define T_SCALE_D 5.0
#define TILE 1024

// ---------------- CSR build ----------------

__global__ void hist_kernel(const int* __restrict__ rows, int* __restrict__ counts, int nnz) {
    int i = blockIdx.x * blockDim.x + threadIdx.x;
    int stride = gridDim.x * blockDim.x;
    for (; i < nnz; i += stride) atomicAdd(&counts[rows[i]], 1);
}

// Pass A: per-1024-tile sums (coalesced loads, LDS tree reduce)
__global__ __launch_bounds__(256) void tile_reduce_kernel(const int* __restrict__ counts,
                                                          int* __restrict__ tile_sums, int N) {
    __shared__ int lds[256];
    int base = blockIdx.x * TILE;
    int t = threadIdx.x;
    int sum = 0;
    for (int i = t; i < TILE; i += 256) {
        int idx = base + i;
        if (idx < N) sum += counts[idx];
    }
    lds[t] = sum;
    __syncthreads();
    for (int off = 128; off > 0; off >>= 1) {
        if (t < off) lds[t] += lds[t + off];
        __syncthreads();
    }
    if (t == 0) tile_sums[blockIdx.x] = lds[0];
}

// Pass B: single-block scan of up to 1024 tile sums -> exclusive tile offsets,
// plus writes row_ptr[N] = total nnz.
__global__ __launch_bounds__(1024) void tile_scan_kernel(const int* __restrict__ tile_sums,
                                                         int* __restrict__ tile_off,
                                                         int* __restrict__ row_ptr_last, int T) {
    __shared__ int lds[1024];
    int t = threadIdx.x;
    int v = (t < T) ? tile_sums[t] : 0;
    lds[t] = v;
    __syncthreads();
    for (int off = 1; off < 1024; off <<= 1) {
        int add = (t >= off) ? lds[t - off] : 0;
        __syncthreads();
        lds[t] += add;
        __syncthreads();
    }
    tile_off[t] = (t == 0) ? 0 : lds[t - 1];
    if (t == 0) *row_ptr_last = lds[1023];
}

// Pass C: per-tile exclusive scan (coalesced) + tile offset -> row_ptr, cursor
__global__ __launch_bounds__(1024) void tile_apply_kernel(const int* __restrict__ counts,
                                                          const int* __restrict__ tile_off,
                                                          int* __restrict__ row_ptr,
                                                          int* __restrict__ cursor, int N) {
    __shared__ int lds[1024];
    int base = blockIdx.x * TILE;
    int t = threadIdx.x;
    int idx = base + t;
    int v = (idx < N) ? counts[idx] : 0;
    lds[t] = v;
    __syncthreads();
    for (int off = 1; off < 1024; off <<= 1) {
        int add = (t >= off) ? lds[t - off] : 0;
        __syncthreads();
        lds[t] += add;
        __syncthreads();
    }
    if (idx < N) {
        int excl = tile_off[blockIdx.x] + lds[t] - v;  // inclusive - self
        row_ptr[idx] = excl;
        cursor[idx] = excl;
    }
}

// Scatter into packed {col, val-bits} entries (one 8B load per edge later)
__global__ void scatter_kernel(const int* __restrict__ rows, const int* __restrict__ cols,
                               const float* __restrict__ vals, int* __restrict__ cursor,
                               int2* __restrict__ cv, int nnz) {
    int i = blockIdx.x * blockDim.x + threadIdx.x;
    int stride = gridDim.x * blockDim.x;
    for (; i < nnz; i += stride) {
        int r = rows[i];
        int p = atomicAdd(&cursor[r], 1);
        cv[p] = make_int2(cols[i], __float_as_int(vals[i]));
    }
}

// ---------------- Chebyshev steps ----------------
// One row per 64-lane group (4 rows per 256-thread block). Lane j owns
// feature j; each edge gather is one coalesced 256B read of t1[col][0:64].
// Edge loop unrolled 8-wide: 8 independent col->gather chains per wave.

#define GATHER8(SRC)                                                          \
    {                                                                         \
        int2 a0 = cv[e], a1 = cv[e + 1], a2 = cv[e + 2], a3 = cv[e + 3];      \
        int2 a4 = cv[e + 4], a5 = cv[e + 5], a6 = cv[e + 6], a7 = cv[e + 7];  \
        float g0 = SRC[((size_t)a0.x << 6) + j];                              \
        float g1 = SRC[((size_t)a1.x << 6) + j];                              \
        float g2 = SRC[((size_t)a2.x << 6) + j];                              \
        float g3 = SRC[((size_t)a3.x << 6) + j];                              \
        float g4 = SRC[((size_t)a4.x << 6) + j];                              \
        float g5 = SRC[((size_t)a5.x << 6) + j];                              \
        float g6 = SRC[((size_t)a6.x << 6) + j];                              \
        float g7 = SRC[((size_t)a7.x << 6) + j];                              \
        s = fmaf(__int_as_float(a0.y), g0, s);                                \
        s = fmaf(__int_as_float(a1.y), g1, s);                                \
        s = fmaf(__int_as_float(a2.y), g2, s);                                \
        s = fmaf(__int_as_float(a3.y), g3, s);                                \
        s = fmaf(__int_as_float(a4.y), g4, s);                                \
        s = fmaf(__int_as_float(a5.y), g5, s);                                \
        s = fmaf(__int_as_float(a6.y), g6, s);                                \
        s = fmaf(__int_as_float(a7.y), g7, s);                                \
    }

// First step: T1 = spmm(X) - X; acc = c0*X + c1*T1 (acc fully overwritten)
__global__ void cheb_first(const float* __restrict__ X, float* __restrict__ t1buf,
                           float* __restrict__ acc, const int* __restrict__ row_ptr,
                           const int2* __restrict__ cv, float c0, float c1, int N) {
    int r = (blockIdx.x << 2) + (threadIdx.x >> 6);
    if (r >= N) return;
    int j = threadIdx.x & 63;
    int e0 = row_ptr[r], e1 = row_ptr[r + 1];
    float s = 0.f;
    int e = e0;
    for (; e + 8 <= e1; e += 8) GATHER8(X);
    for (; e < e1; ++e) {
        int2 a = cv[e];
        s = fmaf(__int_as_float(a.y), X[((size_t)a.x << 6) + j], s);
    }
    int idx = (r << 6) + j;
    float xr = X[idx];
    float t1 = s - xr;
    t1buf[idx] = t1;
    acc[idx] = c0 * xr + c1 * t1;
}

// Generic step: tk = 2*spmm(t1) - 2*t1 - t0; acc += ck*tk; tnew = tk.
// tnew may alias t0 (in-place ping-pong) -> t0/tnew NOT restrict; each t0
// element is read only by the exact thread that writes tnew there.
__global__ void cheb_step(const float* t0, const float* __restrict__ t1,
                          float* tnew, float* __restrict__ acc,
                          const int* __restrict__ row_ptr, const int2* __restrict__ cv,
                          float ck, int N) {
    int r = (blockIdx.x << 2) + (threadIdx.x >> 6);
    if (r >= N) return;
    int j = threadIdx.x & 63;
    int e0 = row_ptr[r], e1 = row_ptr[r + 1];
    float s = 0.f;
    int e = e0;
    for (; e + 8 <= e1; e += 8) GATHER8(t1);
    for (; e < e1; ++e) {
        int2 a = cv[e];
        s = fmaf(__int_as_float(a.y), t1[((size_t)a.x << 6) + j], s);
    }
    int idx = (r << 6) + j;
    float t1r = t1[idx];
    float t0r = t0[idx];
    float tk = 2.f * s - 2.f * t1r - t0r;
    tnew[idx] = tk;
    acc[idx] += ck * tk;
}

extern "C" void kernel_launch(void* const* d_in, const int* in_sizes, int n_in,
                              void* d_out, int out_size, void* d_ws, size_t ws_size,
                              hipStream_t stream) {
    const int* rows = (const int*)d_in[0];
    const int* cols = (const int*)d_in[1];
    const float* vals = (const float*)d_in[2];
    const float* X = (const float*)d_in[3];
    int nnz = in_sizes[0];
    int Nd = in_sizes[3];
    int N = Nd / FEAT;
    float* acc = (float*)d_out;

    char* ws = (char*)d_ws;
    float* B0 = (float*)ws;
    float* B1 = (float*)(ws + (size_t)Nd * 4);
    int* row_ptr = (int*)(ws + (size_t)Nd * 8);       // N+1
    int* cursor = row_ptr + (N + 1);                  // N
    int* counts = cursor + N;                         // N
    int* tile_sums = counts + N;                      // 1024
    int* tile_off = tile_sums + 1024;                 // 1024
    int2* cv = (int2*)(tile_off + 1024);              // nnz (8B aligned: offset is mult of 4B... ensure)
    // ensure 8-byte alignment for cv
    cv = (int2*)((((size_t)cv) + 7) & ~(size_t)7);

    // Static Chebyshev coefficients for exp(-t_scale * lambda), lambda_max=2.
    double c[CHEB_M];
    for (int k = 0; k < CHEB_M; ++k) {
        double sum = 0.0;
        for (int jj = 0; jj < CHEB_M; ++jj) {
            double theta = M_PI * (jj + 0.5) / CHEB_M;
            double lam = cos(theta) + 1.0;  // lambda_max/2 * (x+1)
            sum += exp(-T_SCALE_D * lam) * cos(k * theta);
        }
        c[k] = 2.0 / CHEB_M * sum;
    }
    c[0] *= 0.5;

    int T = (N + TILE - 1) / TILE;  // <= 1024 supported

    // CSR build (every launch)
    hipMemsetAsync(counts, 0, (size_t)N * sizeof(int), stream);
    hist_kernel<<<2048, 256, 0, stream>>>(rows, counts, nnz);
    tile_reduce_kernel<<<T, 256, 0, stream>>>(counts, tile_sums, N);
    tile_scan_kernel<<<1, 1024, 0, stream>>>(tile_sums, tile_off, &row_ptr[N], T);
    tile_apply_kernel<<<T, 1024, 0, stream>>>(counts, tile_off, row_ptr, cursor, N);
    scatter_kernel<<<2048, 256, 0, stream>>>(rows, cols, vals, cursor, cv, nnz);

    int nblk = (N + 3) >> 2;
    // k = 0,1 fused
    cheb_first<<<nblk, 256, 0, stream>>>(X, B0, acc, row_ptr, cv,
                                         (float)c[0], (float)c[1], N);
    // k = 2: t0 = X (read-only input), t1 = B0, write B1
    cheb_step<<<nblk, 256, 0, stream>>>(X, B0, B1, acc, row_ptr, cv, (float)c[2], N);
    // k >= 3: tk overwrites the t0 buffer in place, then swap roles
    const float* t0p = B0;
    const float* t1p = B1;
    for (int k = 3; k < CHEB_M; ++k) {
        cheb_step<<<nblk, 256, 0, stream>>>(t0p, t1p, (float*)t0p, acc, row_ptr,
                                            cv, (float)c[k], N);
        const float* tmp = t0p; t0p = t1p; t1p = tmp;
    }
}

// Round 3
// 2207.819 us; speedup vs baseline: 2.2662x; 1.1541x over previous
//
#include <hip/hip_runtime.h>
#include <math.h>

#define FEAT 64
#define CHEB_M 30
#define T_SCALE_D 5.0
#define TILE 1024

// ---------------- CSR build (rows padded to multiple of 8 edges) ----------------

__global__ void hist_kernel(const int* __restrict__ rows, int* __restrict__ counts, int nnz) {
    int i = blockIdx.x * blockDim.x + threadIdx.x;
    int stride = gridDim.x * blockDim.x;
    for (; i < nnz; i += stride) atomicAdd(&counts[rows[i]], 1);
}

#define PAD8(c) (((c) + 7) & ~7)

// Pass A: per-1024-tile sums of PADDED counts
__global__ __launch_bounds__(256) void tile_reduce_kernel(const int* __restrict__ counts,
                                                          int* __restrict__ tile_sums, int N) {
    __shared__ int lds[256];
    int base = blockIdx.x * TILE;
    int t = threadIdx.x;
    int sum = 0;
    for (int i = t; i < TILE; i += 256) {
        int idx = base + i;
        if (idx < N) sum += PAD8(counts[idx]);
    }
    lds[t] = sum;
    __syncthreads();
    for (int off = 128; off > 0; off >>= 1) {
        if (t < off) lds[t] += lds[t + off];
        __syncthreads();
    }
    if (t == 0) tile_sums[blockIdx.x] = lds[0];
}

// Pass B: single-block scan of tile sums -> exclusive tile offsets + total
__global__ __launch_bounds__(1024) void tile_scan_kernel(const int* __restrict__ tile_sums,
                                                         int* __restrict__ tile_off,
                                                         int* __restrict__ row_ptr_last, int T) {
    __shared__ int lds[1024];
    int t = threadIdx.x;
    int v = (t < T) ? tile_sums[t] : 0;
    lds[t] = v;
    __syncthreads();
    for (int off = 1; off < 1024; off <<= 1) {
        int add = (t >= off) ? lds[t - off] : 0;
        __syncthreads();
        lds[t] += add;
        __syncthreads();
    }
    tile_off[t] = (t == 0) ? 0 : lds[t - 1];
    if (t == 0) *row_ptr_last = lds[1023];
}

// Pass C: per-tile exclusive scan of PADDED counts -> row_ptr, cursor
__global__ __launch_bounds__(1024) void tile_apply_kernel(const int* __restrict__ counts,
                                                          const int* __restrict__ tile_off,
                                                          int* __restrict__ row_ptr,
                                                          int* __restrict__ cursor, int N) {
    __shared__ int lds[1024];
    int base = blockIdx.x * TILE;
    int t = threadIdx.x;
    int idx = base + t;
    int v = (idx < N) ? PAD8(counts[idx]) : 0;
    lds[t] = v;
    __syncthreads();
    for (int off = 1; off < 1024; off <<= 1) {
        int add = (t >= off) ? lds[t - off] : 0;
        __syncthreads();
        lds[t] += add;
        __syncthreads();
    }
    if (idx < N) {
        int excl = tile_off[blockIdx.x] + lds[t] - v;  // inclusive - self
        row_ptr[idx] = excl;
        cursor[idx] = excl;
    }
}

// Scatter into packed {col, val-bits} entries. cv pre-memset to 0, so the
// padding slots at the end of each row are {col=0, val=0.0f} (harmless).
__global__ void scatter_kernel(const int* __restrict__ rows, const int* __restrict__ cols,
                               const float* __restrict__ vals, int* __restrict__ cursor,
                               int2* __restrict__ cv, int nnz) {
    int i = blockIdx.x * blockDim.x + threadIdx.x;
    int stride = gridDim.x * blockDim.x;
    for (; i < nnz; i += stride) {
        int r = rows[i];
        int p = atomicAdd(&cursor[r], 1);
        cv[p] = make_int2(cols[i], __float_as_int(vals[i]));
    }
}

// ---------------- Chebyshev steps ----------------
// One row per 64-lane wave (4 rows per 256-thread block). Lane j owns feature
// j; each edge gather is one coalesced 256B read of SRC[col][0:64]. Rows are
// padded to multiples of 8 edges -> pure 8-wide loop, no tail, uniform MLP=8.
// row_ptr bounds go through readfirstlane so cv chunk addresses are scalar.

#define GATHER8(SRC)                                                          \
    {                                                                         \
        int2 a0 = cv[e], a1 = cv[e + 1], a2 = cv[e + 2], a3 = cv[e + 3];      \
        int2 a4 = cv[e + 4], a5 = cv[e + 5], a6 = cv[e + 6], a7 = cv[e + 7];  \
        float g0 = SRC[(((unsigned)a0.x) << 6) | j];                          \
        float g1 = SRC[(((unsigned)a1.x) << 6) | j];                          \
        float g2 = SRC[(((unsigned)a2.x) << 6) | j];                          \
        float g3 = SRC[(((unsigned)a3.x) << 6) | j];                          \
        float g4 = SRC[(((unsigned)a4.x) << 6) | j];                          \
        float g5 = SRC[(((unsigned)a5.x) << 6) | j];                          \
        float g6 = SRC[(((unsigned)a6.x) << 6) | j];                          \
        float g7 = SRC[(((unsigned)a7.x) << 6) | j];                          \
        s = fmaf(__int_as_float(a0.y), g0, s);                                \
        s = fmaf(__int_as_float(a1.y), g1, s);                                \
        s = fmaf(__int_as_float(a2.y), g2, s);                                \
        s = fmaf(__int_as_float(a3.y), g3, s);                                \
        s = fmaf(__int_as_float(a4.y), g4, s);                                \
        s = fmaf(__int_as_float(a5.y), g5, s);                                \
        s = fmaf(__int_as_float(a6.y), g6, s);                                \
        s = fmaf(__int_as_float(a7.y), g7, s);                                \
    }

// First step: T1 = spmm(X) - X; acc = c0*X + c1*T1 (acc fully overwritten)
__global__ __launch_bounds__(256) void cheb_first(
        const float* __restrict__ X, float* __restrict__ t1buf,
        float* __restrict__ acc, const int* __restrict__ row_ptr,
        const int2* __restrict__ cv, float c0, float c1, int N) {
    int r = (blockIdx.x << 2) + (threadIdx.x >> 6);
    if (r >= N) return;
    unsigned j = threadIdx.x & 63;
    int e0 = __builtin_amdgcn_readfirstlane(row_ptr[r]);
    int e1 = __builtin_amdgcn_readfirstlane(row_ptr[r + 1]);
    float s = 0.f;
    for (int e = e0; e < e1; e += 8) GATHER8(X);
    unsigned idx = (((unsigned)r) << 6) | j;
    float xr = X[idx];
    float t1 = s - xr;
    t1buf[idx] = t1;
    acc[idx] = c0 * xr + c1 * t1;
}

// Generic step: tk = 2*spmm(t1) - 2*t1 - t0; acc += ck*tk; tnew = tk.
// tnew may alias t0 (in-place ping-pong) -> t0/tnew NOT restrict; each t0
// element is read only by the exact thread that writes tnew there.
__global__ __launch_bounds__(256) void cheb_step(
        const float* t0, const float* __restrict__ t1,
        float* tnew, float* __restrict__ acc,
        const int* __restrict__ row_ptr, const int2* __restrict__ cv,
        float ck, int N) {
    int r = (blockIdx.x << 2) + (threadIdx.x >> 6);
    if (r >= N) return;
    unsigned j = threadIdx.x & 63;
    int e0 = __builtin_amdgcn_readfirstlane(row_ptr[r]);
    int e1 = __builtin_amdgcn_readfirstlane(row_ptr[r + 1]);
    float s = 0.f;
    for (int e = e0; e < e1; e += 8) GATHER8(t1);
    unsigned idx = (((unsigned)r) << 6) | j;
    float t1r = t1[idx];
    float t0r = t0[idx];
    float tk = 2.f * s - 2.f * t1r - t0r;
    tnew[idx] = tk;
    acc[idx] += ck * tk;
}

extern "C" void kernel_launch(void* const* d_in, const int* in_sizes, int n_in,
                              void* d_out, int out_size, void* d_ws, size_t ws_size,
                              hipStream_t stream) {
    const int* rows = (const int*)d_in[0];
    const int* cols = (const int*)d_in[1];
    const float* vals = (const float*)d_in[2];
    const float* X = (const float*)d_in[3];
    int nnz = in_sizes[0];
    int Nd = in_sizes[3];
    int N = Nd / FEAT;
    float* acc = (float*)d_out;

    char* ws = (char*)d_ws;
    float* B0 = (float*)ws;
    float* B1 = (float*)(ws + (size_t)Nd * 4);
    int* row_ptr = (int*)(ws + (size_t)Nd * 8);       // N+1
    int* cursor = row_ptr + (N + 1);                  // N
    int* counts = cursor + N;                         // N
    int* tile_sums = counts + N;                      // 1024
    int* tile_off = tile_sums + 1024;                 // 1024
    int2* cv = (int2*)(tile_off + 1024);
    cv = (int2*)((((size_t)cv) + 7) & ~(size_t)7);    // 8B align
    // padded capacity: every row can add up to 7 padding slots
    size_t cv_entries = (size_t)nnz + 7 * (size_t)N + 8;

    // Static Chebyshev coefficients for exp(-t_scale * lambda), lambda_max=2.
    double c[CHEB_M];
    for (int k = 0; k < CHEB_M; ++k) {
        double sum = 0.0;
        for (int jj = 0; jj < CHEB_M; ++jj) {
            double theta = M_PI * (jj + 0.5) / CHEB_M;
            double lam = cos(theta) + 1.0;  // lambda_max/2 * (x+1)
            sum += exp(-T_SCALE_D * lam) * cos(k * theta);
        }
        c[k] = 2.0 / CHEB_M * sum;
    }
    c[0] *= 0.5;

    int T = (N + TILE - 1) / TILE;  // <= 1024 supported

    // CSR build (every launch)
    hipMemsetAsync(counts, 0, (size_t)N * sizeof(int), stream);
    hipMemsetAsync(cv, 0, cv_entries * sizeof(int2), stream);  // padding = {0,0}
    hist_kernel<<<2048, 256, 0, stream>>>(rows, counts, nnz);
    tile_reduce_kernel<<<T, 256, 0, stream>>>(counts, tile_sums, N);
    tile_scan_kernel<<<1, 1024, 0, stream>>>(tile_sums, tile_off, &row_ptr[N], T);
    tile_apply_kernel<<<T, 1024, 0, stream>>>(counts, tile_off, row_ptr, cursor, N);
    scatter_kernel<<<2048, 256, 0, stream>>>(rows, cols, vals, cursor, cv, nnz);

    int nblk = (N + 3) >> 2;
    // k = 0,1 fused
    cheb_first<<<nblk, 256, 0, stream>>>(X, B0, acc, row_ptr, cv,
                                         (float)c[0], (float)c[1], N);
    // k = 2: t0 = X (read-only input), t1 = B0, write B1
    cheb_step<<<nblk, 256, 0, stream>>>(X, B0, B1, acc, row_ptr, cv, (float)c[2], N);
    // k >= 3: tk overwrites the t0 buffer in place, then swap roles
    const float* t0p = B0;
    const float* t1p = B1;
    for (int k = 3; k < CHEB_M; ++k) {
        cheb_step<<<nblk, 256, 0, stream>>>(t0p, t1p, (float*)t0p, acc, row_ptr,
                                            cv, (float)c[k], N);
        const float* tmp = t0p; t0p = t1p; t1p = tmp;
    }
}

// Round 4
// 2202.628 us; speedup vs baseline: 2.2715x; 1.0024x over previous
//
#include <hip/hip_runtime.h>
#include <math.h>

#define FEAT 64
#define CHEB_M 30
#define T_SCALE_D 5.0
#define TILE 1024

// ---------------- CSR build ----------------
// Diagonal entries (row==col) are accumulated into a dense diag[] array and
// excluded from the CSR (general for any COO). Off-diagonal rows padded to a
// multiple of 8 with {col=0, val=0} entries.

__global__ void hist_kernel(const int* __restrict__ rows, const int* __restrict__ cols,
                            const float* __restrict__ vals, int* __restrict__ counts,
                            float* __restrict__ diag, int nnz) {
    int i = blockIdx.x * blockDim.x + threadIdx.x;
    int stride = gridDim.x * blockDim.x;
    for (; i < nnz; i += stride) {
        int r = rows[i];
        if (r == cols[i]) atomicAdd(&diag[r], vals[i]);
        else atomicAdd(&counts[r], 1);
    }
}

#define PAD8(c) (((c) + 7) & ~7)

// Pass A: per-1024-tile sums of PADDED counts
__global__ __launch_bounds__(256) void tile_reduce_kernel(const int* __restrict__ counts,
                                                          int* __restrict__ tile_sums, int N) {
    __shared__ int lds[256];
    int base = blockIdx.x * TILE;
    int t = threadIdx.x;
    int sum = 0;
    for (int i = t; i < TILE; i += 256) {
        int idx = base + i;
        if (idx < N) sum += PAD8(counts[idx]);
    }
    lds[t] = sum;
    __syncthreads();
    for (int off = 128; off > 0; off >>= 1) {
        if (t < off) lds[t] += lds[t + off];
        __syncthreads();
    }
    if (t == 0) tile_sums[blockIdx.x] = lds[0];
}

// Pass B: single-block scan of tile sums -> exclusive tile offsets + total
__global__ __launch_bounds__(1024) void tile_scan_kernel(const int* __restrict__ tile_sums,
                                                         int* __restrict__ tile_off,
                                                         int* __restrict__ row_ptr_last, int T) {
    __shared__ int lds[1024];
    int t = threadIdx.x;
    int v = (t < T) ? tile_sums[t] : 0;
    lds[t] = v;
    __syncthreads();
    for (int off = 1; off < 1024; off <<= 1) {
        int add = (t >= off) ? lds[t - off] : 0;
        __syncthreads();
        lds[t] += add;
        __syncthreads();
    }
    tile_off[t] = (t == 0) ? 0 : lds[t - 1];
    if (t == 0) *row_ptr_last = lds[1023];
}

// Pass C: per-tile exclusive scan of PADDED counts -> row_ptr, cursor
__global__ __launch_bounds__(1024) void tile_apply_kernel(const int* __restrict__ counts,
                                                          const int* __restrict__ tile_off,
                                                          int* __restrict__ row_ptr,
                                                          int* __restrict__ cursor, int N) {
    __shared__ int lds[1024];
    int base = blockIdx.x * TILE;
    int t = threadIdx.x;
    int idx = base + t;
    int v = (idx < N) ? PAD8(counts[idx]) : 0;
    lds[t] = v;
    __syncthreads();
    for (int off = 1; off < 1024; off <<= 1) {
        int add = (t >= off) ? lds[t - off] : 0;
        __syncthreads();
        lds[t] += add;
        __syncthreads();
    }
    if (idx < N) {
        int excl = tile_off[blockIdx.x] + lds[t] - v;  // inclusive - self
        row_ptr[idx] = excl;
        cursor[idx] = excl;
    }
}

// Scatter off-diagonal entries into packed {col, val-bits}. cv pre-memset to
// 0, so padding slots are {col=0, val=0.0f} (harmless: gather X[0], FMA 0).
__global__ void scatter_kernel(const int* __restrict__ rows, const int* __restrict__ cols,
                               const float* __restrict__ vals, int* __restrict__ cursor,
                               int2* __restrict__ cv, int nnz) {
    int i = blockIdx.x * blockDim.x + threadIdx.x;
    int stride = gridDim.x * blockDim.x;
    for (; i < nnz; i += stride) {
        int r = rows[i];
        int c = cols[i];
        if (r == c) continue;
        int p = atomicAdd(&cursor[r], 1);
        cv[p] = make_int2(c, __float_as_int(vals[i]));
    }
}

// ---------------- Chebyshev steps ----------------
// One row per 64-lane wave (4 rows per 256-thread block). Lane j owns feature
// j; each edge gather is one coalesced 256B read of SRC[col][0:64]. Rows are
// padded to multiples of 8; main loop is 16-wide (MLP=16), remainder 8-wide.
// lmul(Y)[r] = sum_offdiag val*Y[col] + (diag[r]-1)*Y[r].

#define GLOAD(K)  float g##K = SRC[(((unsigned)a##K.x) << 6) | j];
#define GFMA(K)   s = fmaf(__int_as_float(a##K.y), g##K, s);

#define GATHER8(SRC)                                                          \
    {                                                                         \
        int2 a0 = cv[e], a1 = cv[e + 1], a2 = cv[e + 2], a3 = cv[e + 3];      \
        int2 a4 = cv[e + 4], a5 = cv[e + 5], a6 = cv[e + 6], a7 = cv[e + 7];  \
        GLOAD(0) GLOAD(1) GLOAD(2) GLOAD(3) GLOAD(4) GLOAD(5) GLOAD(6) GLOAD(7) \
        GFMA(0) GFMA(1) GFMA(2) GFMA(3) GFMA(4) GFMA(5) GFMA(6) GFMA(7)       \
    }

#define GATHER16(SRC)                                                         \
    {                                                                         \
        int2 a0 = cv[e], a1 = cv[e + 1], a2 = cv[e + 2], a3 = cv[e + 3];      \
        int2 a4 = cv[e + 4], a5 = cv[e + 5], a6 = cv[e + 6], a7 = cv[e + 7];  \
        int2 a8 = cv[e + 8], a9 = cv[e + 9], a10 = cv[e + 10], a11 = cv[e + 11]; \
        int2 a12 = cv[e + 12], a13 = cv[e + 13], a14 = cv[e + 14], a15 = cv[e + 15]; \
        GLOAD(0) GLOAD(1) GLOAD(2) GLOAD(3) GLOAD(4) GLOAD(5) GLOAD(6) GLOAD(7) \
        GLOAD(8) GLOAD(9) GLOAD(10) GLOAD(11) GLOAD(12) GLOAD(13) GLOAD(14) GLOAD(15) \
        GFMA(0) GFMA(1) GFMA(2) GFMA(3) GFMA(4) GFMA(5) GFMA(6) GFMA(7)       \
        GFMA(8) GFMA(9) GFMA(10) GFMA(11) GFMA(12) GFMA(13) GFMA(14) GFMA(15) \
    }

// First step: T1 = lmul(X); acc = c0*X + c1*T1 (acc fully overwritten)
__global__ __launch_bounds__(256) void cheb_first(
        const float* __restrict__ X, float* __restrict__ t1buf,
        float* __restrict__ acc, const int* __restrict__ row_ptr,
        const int2* __restrict__ cv, const float* __restrict__ diag,
        float c0, float c1, int N) {
    int r = (blockIdx.x << 2) + (threadIdx.x >> 6);
    if (r >= N) return;
    unsigned j = threadIdx.x & 63;
    int e0 = __builtin_amdgcn_readfirstlane(row_ptr[r]);
    int e1 = __builtin_amdgcn_readfirstlane(row_ptr[r + 1]);
    float dm1 = diag[r] - 1.0f;
    float s = 0.f;
    int e = e0;
    {
        const float* __restrict__ SRC = X;
        for (; e + 16 <= e1; e += 16) GATHER16(SRC);
        if (e < e1) GATHER8(SRC);  // padded to 8 -> remainder is exactly 8
    }
    unsigned idx = (((unsigned)r) << 6) | j;
    float xr = X[idx];
    float t1 = fmaf(dm1, xr, s);
    t1buf[idx] = t1;
    acc[idx] = c0 * xr + c1 * t1;
}

// Generic step: tk = 2*lmul(t1) - t0; acc += ck*tk; tnew = tk.
// tnew may alias t0 (in-place ping-pong) -> t0/tnew NOT restrict; each t0
// element is read only by the exact thread that writes tnew there.
__global__ __launch_bounds__(256) void cheb_step(
        const float* t0, const float* __restrict__ t1,
        float* tnew, float* __restrict__ acc,
        const int* __restrict__ row_ptr, const int2* __restrict__ cv,
        const float* __restrict__ diag, float ck, int N) {
    int r = (blockIdx.x << 2) + (threadIdx.x >> 6);
    if (r >= N) return;
    unsigned j = threadIdx.x & 63;
    int e0 = __builtin_amdgcn_readfirstlane(row_ptr[r]);
    int e1 = __builtin_amdgcn_readfirstlane(row_ptr[r + 1]);
    float dm1 = diag[r] - 1.0f;
    float s = 0.f;
    int e = e0;
    {
        const float* __restrict__ SRC = t1;
        for (; e + 16 <= e1; e += 16) GATHER16(SRC);
        if (e < e1) GATHER8(SRC);
    }
    unsigned idx = (((unsigned)r) << 6) | j;
    float t1r = t1[idx];
    float t0r = t0[idx];
    float tk = 2.f * fmaf(dm1, t1r, s) - t0r;
    tnew[idx] = tk;
    acc[idx] += ck * tk;
}

extern "C" void kernel_launch(void* const* d_in, const int* in_sizes, int n_in,
                              void* d_out, int out_size, void* d_ws, size_t ws_size,
                              hipStream_t stream) {
    const int* rows = (const int*)d_in[0];
    const int* cols = (const int*)d_in[1];
    const float* vals = (const float*)d_in[2];
    const float* X = (const float*)d_in[3];
    int nnz = in_sizes[0];
    int Nd = in_sizes[3];
    int N = Nd / FEAT;
    float* acc = (float*)d_out;

    char* ws = (char*)d_ws;
    float* B0 = (float*)ws;
    float* B1 = (float*)(ws + (size_t)Nd * 4);
    int* row_ptr = (int*)(ws + (size_t)Nd * 8);       // N+1
    int* cursor = row_ptr + (N + 1);                  // N
    int* counts = cursor + N;                         // N
    int* tile_sums = counts + N;                      // 1024
    int* tile_off = tile_sums + 1024;                 // 1024
    float* diag = (float*)(tile_off + 1024);          // N
    int2* cv = (int2*)(diag + N);
    cv = (int2*)((((size_t)cv) + 7) & ~(size_t)7);    // 8B align
    // padded capacity: every row can add up to 7 padding slots
    size_t cv_entries = (size_t)nnz + 7 * (size_t)N + 8;

    // Static Chebyshev coefficients for exp(-t_scale * lambda), lambda_max=2.
    double c[CHEB_M];
    for (int k = 0; k < CHEB_M; ++k) {
        double sum = 0.0;
        for (int jj = 0; jj < CHEB_M; ++jj) {
            double theta = M_PI * (jj + 0.5) / CHEB_M;
            double lam = cos(theta) + 1.0;  // lambda_max/2 * (x+1)
            sum += exp(-T_SCALE_D * lam) * cos(k * theta);
        }
        c[k] = 2.0 / CHEB_M * sum;
    }
    c[0] *= 0.5;

    int T = (N + TILE - 1) / TILE;  // <= 1024 supported

    // CSR build (every launch)
    hipMemsetAsync(counts, 0, (size_t)N * sizeof(int), stream);
    hipMemsetAsync(diag, 0, (size_t)N * sizeof(float), stream);
    hipMemsetAsync(cv, 0, cv_entries * sizeof(int2), stream);  // padding = {0,0}
    hist_kernel<<<2048, 256, 0, stream>>>(rows, cols, vals, counts, diag, nnz);
    tile_reduce_kernel<<<T, 256, 0, stream>>>(counts, tile_sums, N);
    tile_scan_kernel<<<1, 1024, 0, stream>>>(tile_sums, tile_off, &row_ptr[N], T);
    tile_apply_kernel<<<T, 1024, 0, stream>>>(counts, tile_off, row_ptr, cursor, N);
    scatter_kernel<<<2048, 256, 0, stream>>>(rows, cols, vals, cursor, cv, nnz);

    int nblk = (N + 3) >> 2;
    // k = 0,1 fused
    cheb_first<<<nblk, 256, 0, stream>>>(X, B0, acc, row_ptr, cv, diag,
                                         (float)c[0], (float)c[1], N);
    // k = 2: t0 = X (read-only input), t1 = B0, write B1
    cheb_step<<<nblk, 256, 0, stream>>>(X, B0, B1, acc, row_ptr, cv, diag,
                                        (float)c[2], N);
    // k >= 3: tk overwrites the t0 buffer in place, then swap roles
    const float* t0p = B0;
    const float* t1p = B1;
    for (int k = 3; k < CHEB_M; ++k) {
        cheb_step<<<nblk, 256, 0, stream>>>(t0p, t1p, (float*)t0p, acc, row_ptr,
                                            cv, diag, (float)c[k], N);
        const float* tmp = t0p; t0p = t1p; t1p = tmp;
    }
}